// Round 2
// baseline (149.116 us; speedup 1.0000x reference)
//
#include <hip/hip_runtime.h>

#define Bn 4
#define Tn 16
#define Nn 50000
#define Cn 16
#define En 50000
#define LAM 0.3f
#define COS_EPS 1e-8f
#define NORM_EPS 1e-8f

// Kernel 1: feat_hat[b][n][0:16]=mean/norm, [16:32]=std/norm  (normalized rows)
// thread = (b, n, c4) with c4 = 4-channel chunk; lanes: c4 fastest -> coalesced float4
__global__ void feat_kernel(const float* __restrict__ x, float* __restrict__ feat) {
    int gid = blockIdx.x * blockDim.x + threadIdx.x;
    if (gid >= Bn * Nn * 4) return;
    int c4 = gid & 3;
    int bn = gid >> 2;            // b*N + n
    int b  = bn / Nn;
    int n  = bn - b * Nn;

    const float4* x4 = (const float4*)x;
    float4 s  = make_float4(0.f, 0.f, 0.f, 0.f);
    float4 ss = make_float4(0.f, 0.f, 0.f, 0.f);
    int base = (b * Tn) * Nn;     // row units of 16 floats
#pragma unroll
    for (int t = 0; t < Tn; ++t) {
        float4 v = x4[(base + t * Nn + n) * 4 + c4];
        s.x += v.x; s.y += v.y; s.z += v.z; s.w += v.w;
        ss.x += v.x * v.x; ss.y += v.y * v.y; ss.z += v.z * v.z; ss.w += v.w * v.w;
    }
    const float inv = 1.0f / (float)Tn;
    float4 m, sd;
    m.x = s.x * inv; m.y = s.y * inv; m.z = s.z * inv; m.w = s.w * inv;
    sd.x = sqrtf(fmaxf(ss.x * inv - m.x * m.x, 0.f));
    sd.y = sqrtf(fmaxf(ss.y * inv - m.y * m.y, 0.f));
    sd.z = sqrtf(fmaxf(ss.z * inv - m.z * m.z, 0.f));
    sd.w = sqrtf(fmaxf(ss.w * inv - m.w * m.w, 0.f));

    // partial norm^2 of this lane's 8 features, reduce over 4 lanes sharing n
    float p = m.x * m.x + m.y * m.y + m.z * m.z + m.w * m.w
            + sd.x * sd.x + sd.y * sd.y + sd.z * sd.z + sd.w * sd.w;
    p += __shfl_xor(p, 1);
    p += __shfl_xor(p, 2);
    float rn = 1.0f / fmaxf(sqrtf(p), COS_EPS);

    float4* f4 = (float4*)feat;
    int ob = bn * 8;
    float4 om  = make_float4(m.x * rn, m.y * rn, m.z * rn, m.w * rn);
    float4 osd = make_float4(sd.x * rn, sd.y * rn, sd.z * rn, sd.w * rn);
    f4[ob + c4]     = om;
    f4[ob + 4 + c4] = osd;
}

// Kernel 2: mean cosine sim per (b, e). feat rows are unit vectors -> sim = clamp(dot,0,1)
__global__ void edge_sim_kernel(const float* __restrict__ feat,
                                const int* __restrict__ members,
                                const int* __restrict__ centers,
                                const int* __restrict__ offsets,
                                float* __restrict__ ms) {
    int gid = blockIdx.x * blockDim.x + threadIdx.x;
    if (gid >= Bn * En) return;
    int b = gid / En;
    int e = gid - b * En;

    int off0 = offsets[e];
    int off1 = offsets[e + 1];
    int cn   = centers[e];

    const float4* f4 = (const float4*)feat;
    int cb = (b * Nn + cn) * 8;
    float4 c0 = f4[cb + 0], c1 = f4[cb + 1], c2 = f4[cb + 2], c3 = f4[cb + 3];
    float4 c4v = f4[cb + 4], c5 = f4[cb + 5], c6 = f4[cb + 6], c7 = f4[cb + 7];

    float ssum = 0.f;
    for (int j = off0; j < off1; ++j) {
        int mn = members[j];
        int mb = (b * Nn + mn) * 8;
        float d = 0.f;
        float4 v;
        v = f4[mb + 0]; d += v.x * c0.x + v.y * c0.y + v.z * c0.z + v.w * c0.w;
        v = f4[mb + 1]; d += v.x * c1.x + v.y * c1.y + v.z * c1.z + v.w * c1.w;
        v = f4[mb + 2]; d += v.x * c2.x + v.y * c2.y + v.z * c2.z + v.w * c2.w;
        v = f4[mb + 3]; d += v.x * c3.x + v.y * c3.y + v.z * c3.z + v.w * c3.w;
        v = f4[mb + 4]; d += v.x * c4v.x + v.y * c4v.y + v.z * c4v.z + v.w * c4v.w;
        v = f4[mb + 5]; d += v.x * c5.x + v.y * c5.y + v.z * c5.z + v.w * c5.w;
        v = f4[mb + 6]; d += v.x * c6.x + v.y * c6.y + v.z * c6.z + v.w * c6.w;
        v = f4[mb + 7]; d += v.x * c7.x + v.y * c7.y + v.z * c7.z + v.w * c7.w;
        ssum += fminf(fmaxf(d, 0.f), 1.f);
    }
    int deg = off1 - off0;
    ms[gid] = ssum / fmaxf((float)deg, 1.0f);
}

// Kernel 3: per-batch min/max of mean_sim
__global__ void minmax_kernel(const float* __restrict__ ms, float* __restrict__ mm) {
    int b = blockIdx.x;
    const float* p = ms + b * En;
    float lo = INFINITY, hi = -INFINITY;
    for (int i = threadIdx.x; i < En; i += blockDim.x) {
        float v = p[i];
        lo = fminf(lo, v);
        hi = fmaxf(hi, v);
    }
#pragma unroll
    for (int m = 1; m < 64; m <<= 1) {
        lo = fminf(lo, __shfl_xor(lo, m));
        hi = fmaxf(hi, __shfl_xor(hi, m));
    }
    __shared__ float slo[16], shi[16];
    int wid  = threadIdx.x >> 6;
    int lane = threadIdx.x & 63;
    if (lane == 0) { slo[wid] = lo; shi[wid] = hi; }
    __syncthreads();
    if (threadIdx.x == 0) {
        int nw = blockDim.x >> 6;
        float flo = slo[0], fhi = shi[0];
        for (int i = 1; i < nw; ++i) { flo = fminf(flo, slo[i]); fhi = fmaxf(fhi, shi[i]); }
        mm[b * 2]     = flo;
        mm[b * 2 + 1] = fhi;
    }
}

// Kernel 4: out = W * (1 + LAM * minmax-normed mean_sim)
__global__ void out_kernel(const float* __restrict__ ms, const float* __restrict__ mm,
                           const float* __restrict__ W, float* __restrict__ out) {
    int gid = blockIdx.x * blockDim.x + threadIdx.x;
    if (gid >= Bn * En) return;
    int b = gid / En;
    int e = gid - b * En;
    float smin = mm[b * 2];
    float smax = mm[b * 2 + 1];
    float v = (ms[gid] - smin) / (smax - smin + NORM_EPS);
    out[gid] = W[e] * (1.0f + LAM * v);
}

extern "C" void kernel_launch(void* const* d_in, const int* in_sizes, int n_in,
                              void* d_out, int out_size, void* d_ws, size_t ws_size,
                              hipStream_t stream) {
    const float* x_raw        = (const float*)d_in[0];
    // d_in[1] = H, unused
    const float* W            = (const float*)d_in[2];
    const int*   edge_members = (const int*)d_in[3];
    const int*   edge_centers = (const int*)d_in[4];
    const int*   edge_offsets = (const int*)d_in[5];
    float*       out          = (float*)d_out;

    float* feat = (float*)d_ws;                          // B*N*32 floats = 25.6 MB
    float* ms   = feat + (size_t)Bn * Nn * 32;           // B*E floats
    float* mm   = ms + (size_t)Bn * En;                  // 2*B floats

    {
        int total = Bn * Nn * 4;
        feat_kernel<<<(total + 255) / 256, 256, 0, stream>>>(x_raw, feat);
    }
    {
        int total = Bn * En;
        edge_sim_kernel<<<(total + 255) / 256, 256, 0, stream>>>(
            feat, edge_members, edge_centers, edge_offsets, ms);
    }
    minmax_kernel<<<Bn, 1024, 0, stream>>>(ms, mm);
    {
        int total = Bn * En;
        out_kernel<<<(total + 255) / 256, 256, 0, stream>>>(ms, mm, W, out);
    }
}

// Round 3
// 118.927 us; speedup vs baseline: 1.2538x; 1.2538x over previous
//
#include <hip/hip_runtime.h>

#define Bn 4
#define Tn 16
#define Nn 50000
#define Cn 16
#define En 50000
#define LAM 0.3f
#define COS_EPS 1e-8f
#define NORM_EPS 1e-8f

// Kernel 1: feat_hat[b][n][0:16]=mean/norm, [16:32]=std/norm  (normalized rows)
// thread = (b, n, c4) with c4 = 4-channel chunk; lanes: c4 fastest -> coalesced float4
__global__ void feat_kernel(const float* __restrict__ x, float* __restrict__ feat) {
    int gid = blockIdx.x * blockDim.x + threadIdx.x;
    if (gid >= Bn * Nn * 4) return;
    int c4 = gid & 3;
    int bn = gid >> 2;            // b*N + n
    int b  = bn / Nn;
    int n  = bn - b * Nn;

    const float4* x4 = (const float4*)x;
    float4 s  = make_float4(0.f, 0.f, 0.f, 0.f);
    float4 ss = make_float4(0.f, 0.f, 0.f, 0.f);
    int base = (b * Tn) * Nn;     // row units of 16 floats
#pragma unroll
    for (int t = 0; t < Tn; ++t) {
        float4 v = x4[(base + t * Nn + n) * 4 + c4];
        s.x += v.x; s.y += v.y; s.z += v.z; s.w += v.w;
        ss.x += v.x * v.x; ss.y += v.y * v.y; ss.z += v.z * v.z; ss.w += v.w * v.w;
    }
    const float inv = 1.0f / (float)Tn;
    float4 m, sd;
    m.x = s.x * inv; m.y = s.y * inv; m.z = s.z * inv; m.w = s.w * inv;
    sd.x = sqrtf(fmaxf(ss.x * inv - m.x * m.x, 0.f));
    sd.y = sqrtf(fmaxf(ss.y * inv - m.y * m.y, 0.f));
    sd.z = sqrtf(fmaxf(ss.z * inv - m.z * m.z, 0.f));
    sd.w = sqrtf(fmaxf(ss.w * inv - m.w * m.w, 0.f));

    // partial norm^2 of this lane's 8 features, reduce over 4 lanes sharing n
    float p = m.x * m.x + m.y * m.y + m.z * m.z + m.w * m.w
            + sd.x * sd.x + sd.y * sd.y + sd.z * sd.z + sd.w * sd.w;
    p += __shfl_xor(p, 1);
    p += __shfl_xor(p, 2);
    float rn = 1.0f / fmaxf(sqrtf(p), COS_EPS);

    float4* f4 = (float4*)feat;
    int ob = bn * 8;
    float4 om  = make_float4(m.x * rn, m.y * rn, m.z * rn, m.w * rn);
    float4 osd = make_float4(sd.x * rn, sd.y * rn, sd.z * rn, sd.w * rn);
    f4[ob + c4]     = om;
    f4[ob + 4 + c4] = osd;
}

// Kernel 2: one WAVE per (b,e). 64 lanes = 16 members x 4 lanes.
// Lane l: group g=l>>2 (member slot), q=l&3 (channel quad).
// Wave fetches all 16 member rows in 2 coalesced float4 loads.
__global__ void edge_sim_kernel(const float* __restrict__ feat,
                                const int* __restrict__ members,
                                const int* __restrict__ centers,
                                const int* __restrict__ offsets,
                                float* __restrict__ ms) {
    int tid  = blockIdx.x * blockDim.x + threadIdx.x;
    int wid  = tid >> 6;                  // global wave id = b*En + e
    if (wid >= Bn * En) return;
    int lane = threadIdx.x & 63;
    int g    = lane >> 2;
    int q    = lane & 3;
    int b    = wid / En;
    int e    = wid - b * En;

    int off0 = offsets[e];
    int off1 = offsets[e + 1];
    int deg  = off1 - off0;
    int cn   = centers[e];

    const float4* f4 = (const float4*)feat;
    int cb = (b * Nn + cn) * 8;
    float4 c1 = f4[cb + q];
    float4 c2 = f4[cb + 4 + q];

    float ssum = 0.f;
    // deg is 16 here; loop handles general deg in strides of 16
    for (int m0 = g; m0 < deg; m0 += 16) {
        int mn = members[off0 + m0];
        int mb = (b * Nn + mn) * 8;
        float4 v1 = f4[mb + q];
        float4 v2 = f4[mb + 4 + q];
        float d = v1.x * c1.x + v1.y * c1.y + v1.z * c1.z + v1.w * c1.w
                + v2.x * c2.x + v2.y * c2.y + v2.z * c2.z + v2.w * c2.w;
        // reduce over the 4-lane group -> full dot in all 4 lanes
        d += __shfl_xor(d, 1);
        d += __shfl_xor(d, 2);
        ssum += fminf(fmaxf(d, 0.f), 1.f);
    }
    // every lane of a group holds the group's sim sum -> scale by 1/4, wave-reduce
    ssum *= 0.25f;
#pragma unroll
    for (int m = 4; m < 64; m <<= 1) ssum += __shfl_xor(ssum, m);

    if (lane == 0) ms[wid] = ssum / fmaxf((float)deg, 1.0f);
}

// Kernel 3: per-batch min/max of mean_sim
__global__ void minmax_kernel(const float* __restrict__ ms, float* __restrict__ mm) {
    int b = blockIdx.x;
    const float* p = ms + b * En;
    float lo = INFINITY, hi = -INFINITY;
    for (int i = threadIdx.x; i < En; i += blockDim.x) {
        float v = p[i];
        lo = fminf(lo, v);
        hi = fmaxf(hi, v);
    }
#pragma unroll
    for (int m = 1; m < 64; m <<= 1) {
        lo = fminf(lo, __shfl_xor(lo, m));
        hi = fmaxf(hi, __shfl_xor(hi, m));
    }
    __shared__ float slo[16], shi[16];
    int wid  = threadIdx.x >> 6;
    int lane = threadIdx.x & 63;
    if (lane == 0) { slo[wid] = lo; shi[wid] = hi; }
    __syncthreads();
    if (threadIdx.x == 0) {
        int nw = blockDim.x >> 6;
        float flo = slo[0], fhi = shi[0];
        for (int i = 1; i < nw; ++i) { flo = fminf(flo, slo[i]); fhi = fmaxf(fhi, shi[i]); }
        mm[b * 2]     = flo;
        mm[b * 2 + 1] = fhi;
    }
}

// Kernel 4: out = W * (1 + LAM * minmax-normed mean_sim)
__global__ void out_kernel(const float* __restrict__ ms, const float* __restrict__ mm,
                           const float* __restrict__ W, float* __restrict__ out) {
    int gid = blockIdx.x * blockDim.x + threadIdx.x;
    if (gid >= Bn * En) return;
    int b = gid / En;
    int e = gid - b * En;
    float smin = mm[b * 2];
    float smax = mm[b * 2 + 1];
    float v = (ms[gid] - smin) / (smax - smin + NORM_EPS);
    out[gid] = W[e] * (1.0f + LAM * v);
}

extern "C" void kernel_launch(void* const* d_in, const int* in_sizes, int n_in,
                              void* d_out, int out_size, void* d_ws, size_t ws_size,
                              hipStream_t stream) {
    const float* x_raw        = (const float*)d_in[0];
    // d_in[1] = H, unused
    const float* W            = (const float*)d_in[2];
    const int*   edge_members = (const int*)d_in[3];
    const int*   edge_centers = (const int*)d_in[4];
    const int*   edge_offsets = (const int*)d_in[5];
    float*       out          = (float*)d_out;

    float* feat = (float*)d_ws;                          // B*N*32 floats = 25.6 MB
    float* ms   = feat + (size_t)Bn * Nn * 32;           // B*E floats
    float* mm   = ms + (size_t)Bn * En;                  // 2*B floats

    {
        int total = Bn * Nn * 4;
        feat_kernel<<<(total + 255) / 256, 256, 0, stream>>>(x_raw, feat);
    }
    {
        // one wave (64 threads) per (b,e): B*E waves
        long long threads = (long long)Bn * En * 64;
        int blocks = (int)((threads + 255) / 256);
        edge_sim_kernel<<<blocks, 256, 0, stream>>>(
            feat, edge_members, edge_centers, edge_offsets, ms);
    }
    minmax_kernel<<<Bn, 1024, 0, stream>>>(ms, mm);
    {
        int total = Bn * En;
        out_kernel<<<(total + 255) / 256, 256, 0, stream>>>(ms, mm, W, out);
    }
}

// Round 4
// 102.549 us; speedup vs baseline: 1.4541x; 1.1597x over previous
//
#include <hip/hip_runtime.h>

#define Bn 4
#define Tn 16
#define Nn 50000
#define Cn 16
#define En 50000
#define LAM 0.3f
#define COS_EPS 1e-8f
#define NORM_EPS 1e-8f

// Kernel 1: feat_hat[b][n][0:16]=mean/norm, [16:32]=std/norm  (normalized rows)
// thread = (b, n, c4); lanes: c4 fastest -> coalesced float4.
// Also re-initializes the global min/max cells (mm) every launch (replay-safe).
__global__ void feat_kernel(const float* __restrict__ x, float* __restrict__ feat,
                            unsigned* __restrict__ mm) {
    if (blockIdx.x == 0 && threadIdx.x < 2 * Bn) {
        // even = min slot (init +inf bits), odd = max slot (init 0)
        mm[threadIdx.x] = (threadIdx.x & 1) ? 0u : 0x7F800000u;
    }
    int gid = blockIdx.x * blockDim.x + threadIdx.x;
    if (gid >= Bn * Nn * 4) return;
    int c4 = gid & 3;
    int bn = gid >> 2;            // b*N + n
    int b  = bn / Nn;
    int n  = bn - b * Nn;

    const float4* x4 = (const float4*)x;
    float4 s  = make_float4(0.f, 0.f, 0.f, 0.f);
    float4 ss = make_float4(0.f, 0.f, 0.f, 0.f);
    int base = (b * Tn) * Nn;     // row units of 16 floats
#pragma unroll
    for (int t = 0; t < Tn; ++t) {
        float4 v = x4[(base + t * Nn + n) * 4 + c4];
        s.x += v.x; s.y += v.y; s.z += v.z; s.w += v.w;
        ss.x += v.x * v.x; ss.y += v.y * v.y; ss.z += v.z * v.z; ss.w += v.w * v.w;
    }
    const float inv = 1.0f / (float)Tn;
    float4 m, sd;
    m.x = s.x * inv; m.y = s.y * inv; m.z = s.z * inv; m.w = s.w * inv;
    sd.x = sqrtf(fmaxf(ss.x * inv - m.x * m.x, 0.f));
    sd.y = sqrtf(fmaxf(ss.y * inv - m.y * m.y, 0.f));
    sd.z = sqrtf(fmaxf(ss.z * inv - m.z * m.z, 0.f));
    sd.w = sqrtf(fmaxf(ss.w * inv - m.w * m.w, 0.f));

    float p = m.x * m.x + m.y * m.y + m.z * m.z + m.w * m.w
            + sd.x * sd.x + sd.y * sd.y + sd.z * sd.z + sd.w * sd.w;
    p += __shfl_xor(p, 1);
    p += __shfl_xor(p, 2);
    float rn = 1.0f / fmaxf(sqrtf(p), COS_EPS);

    float4* f4 = (float4*)feat;
    int ob = bn * 8;
    float4 om  = make_float4(m.x * rn, m.y * rn, m.z * rn, m.w * rn);
    float4 osd = make_float4(sd.x * rn, sd.y * rn, sd.z * rn, sd.w * rn);
    f4[ob + c4]     = om;
    f4[ob + 4 + c4] = osd;
}

// Kernel 2: one WAVE per edge e, covering ALL 4 batches (4 independent
// load->dot->shfl chains per wave for MLP). Lane l: g=l>>2 member slot,
// q=l&3 channel quad. Member-row gathers are 64B segments (4 lanes x 16B).
__global__ void edge_sim_kernel(const float* __restrict__ feat,
                                const int* __restrict__ members,
                                const int* __restrict__ centers,
                                const int* __restrict__ offsets,
                                float* __restrict__ ms) {
    int tid  = blockIdx.x * blockDim.x + threadIdx.x;
    int e    = tid >> 6;
    if (e >= En) return;
    int lane = threadIdx.x & 63;
    int g    = lane >> 2;
    int q    = lane & 3;

    int off0 = offsets[e];
    int off1 = offsets[e + 1];
    int deg  = off1 - off0;
    int cn   = centers[e];

    const float4* f4 = (const float4*)feat;
    float4 cA[Bn], cB[Bn];
#pragma unroll
    for (int b_ = 0; b_ < Bn; ++b_) {
        int cb = (b_ * Nn + cn) * 8;
        cA[b_] = f4[cb + q];
        cB[b_] = f4[cb + 4 + q];
    }

    float sums[Bn] = {0.f, 0.f, 0.f, 0.f};
    for (int m0 = g; m0 < deg; m0 += 16) {
        int mn = members[off0 + m0];
#pragma unroll
        for (int b_ = 0; b_ < Bn; ++b_) {
            int mb = (b_ * Nn + mn) * 8;
            float4 v1 = f4[mb + q];
            float4 v2 = f4[mb + 4 + q];
            float d = v1.x * cA[b_].x + v1.y * cA[b_].y + v1.z * cA[b_].z + v1.w * cA[b_].w
                    + v2.x * cB[b_].x + v2.y * cB[b_].y + v2.z * cB[b_].z + v2.w * cB[b_].w;
            d += __shfl_xor(d, 1);
            d += __shfl_xor(d, 2);   // all 4 lanes of group g hold full dot
            sums[b_] += fminf(fmaxf(d, 0.f), 1.f);
        }
    }
    // Each q-lane-class holds one copy per member group -> reduce strides 4..32.
#pragma unroll
    for (int b_ = 0; b_ < Bn; ++b_) {
        float s = sums[b_];
        s += __shfl_xor(s, 4);
        s += __shfl_xor(s, 8);
        s += __shfl_xor(s, 16);
        s += __shfl_xor(s, 32);
        sums[b_] = s;
    }
    if (lane == 0) {
        float invd = 1.0f / fmaxf((float)deg, 1.0f);
#pragma unroll
        for (int b_ = 0; b_ < Bn; ++b_) ms[b_ * En + e] = sums[b_] * invd;
    }
}

// Kernel 3: per-batch min/max via uint-bit atomics (valid: values >= 0).
// 64 blocks per batch; block-local reduce -> 2 atomics per block.
__global__ void minmax_kernel(const float* __restrict__ ms, unsigned* __restrict__ mm) {
    int b = blockIdx.x >> 6;          // 64 blocks per batch
    int j = blockIdx.x & 63;
    const float* p = ms + b * En;
    float lo = INFINITY, hi = 0.f;
    for (int i = j * blockDim.x + threadIdx.x; i < En; i += 64 * 256) {
        float v = p[i];
        lo = fminf(lo, v);
        hi = fmaxf(hi, v);
    }
#pragma unroll
    for (int m = 1; m < 64; m <<= 1) {
        lo = fminf(lo, __shfl_xor(lo, m));
        hi = fmaxf(hi, __shfl_xor(hi, m));
    }
    __shared__ float slo[4], shi[4];
    int wid  = threadIdx.x >> 6;
    int lane = threadIdx.x & 63;
    if (lane == 0) { slo[wid] = lo; shi[wid] = hi; }
    __syncthreads();
    if (threadIdx.x == 0) {
        float flo = fminf(fminf(slo[0], slo[1]), fminf(slo[2], slo[3]));
        float fhi = fmaxf(fmaxf(shi[0], shi[1]), fmaxf(shi[2], shi[3]));
        atomicMin(&mm[b * 2],     __float_as_uint(flo));
        atomicMax(&mm[b * 2 + 1], __float_as_uint(fhi));
    }
}

// Kernel 4: out = W * (1 + LAM * minmax-normed mean_sim)
__global__ void out_kernel(const float* __restrict__ ms, const unsigned* __restrict__ mm,
                           const float* __restrict__ W, float* __restrict__ out) {
    int gid = blockIdx.x * blockDim.x + threadIdx.x;
    if (gid >= Bn * En) return;
    int b = gid / En;
    int e = gid - b * En;
    float smin = __uint_as_float(mm[b * 2]);
    float smax = __uint_as_float(mm[b * 2 + 1]);
    float v = (ms[gid] - smin) / (smax - smin + NORM_EPS);
    out[gid] = W[e] * (1.0f + LAM * v);
}

extern "C" void kernel_launch(void* const* d_in, const int* in_sizes, int n_in,
                              void* d_out, int out_size, void* d_ws, size_t ws_size,
                              hipStream_t stream) {
    const float* x_raw        = (const float*)d_in[0];
    // d_in[1] = H, unused
    const float* W            = (const float*)d_in[2];
    const int*   edge_members = (const int*)d_in[3];
    const int*   edge_centers = (const int*)d_in[4];
    const int*   edge_offsets = (const int*)d_in[5];
    float*       out          = (float*)d_out;

    float*    feat = (float*)d_ws;                       // B*N*32 floats = 25.6 MB
    float*    ms   = feat + (size_t)Bn * Nn * 32;        // B*E floats
    unsigned* mm   = (unsigned*)(ms + (size_t)Bn * En);  // 2*B uints

    {
        int total = Bn * Nn * 4;
        feat_kernel<<<(total + 255) / 256, 256, 0, stream>>>(x_raw, feat, mm);
    }
    {
        // one wave (64 threads) per edge: En waves
        long long threads = (long long)En * 64;
        int blocks = (int)((threads + 255) / 256);
        edge_sim_kernel<<<blocks, 256, 0, stream>>>(
            feat, edge_members, edge_centers, edge_offsets, ms);
    }
    minmax_kernel<<<Bn * 64, 256, 0, stream>>>(ms, mm);
    {
        int total = Bn * En;
        out_kernel<<<(total + 255) / 256, 256, 0, stream>>>(ms, mm, W, out);
    }
}

// Round 5
// 77.553 us; speedup vs baseline: 1.9228x; 1.3223x over previous
//
#include <hip/hip_runtime.h>
#include <hip/hip_fp16.h>

#define Bn 4
#define Tn 16
#define Nn 50000
#define Cn 16
#define En 50000
#define LAM 0.3f
#define COS_EPS 1e-8f
#define NORM_EPS 1e-8f

// fp16 feature table, node-major: feat[n][b][32] halves, row = 64 B.
// Row layout per (n,b): chunk c4 in 0..3 holds [mu[4c4..+3], sd[4c4..+3]]
// (fixed permutation of the 32 features; consistent for member & center).
union H8 { __half2 h2[4]; float4 f4; };

// Kernel 1: thread = (b*N+n, c4); x reads stay fully coalesced (1KB/wave),
// each thread emits one contiguous 16 B half8 chunk.
// Also re-inits the global min/max cells every launch (replay-safe).
__global__ void feat_kernel(const float* __restrict__ x, float4* __restrict__ feat,
                            unsigned* __restrict__ mm) {
    if (blockIdx.x == 0 && threadIdx.x < 2 * Bn) {
        mm[threadIdx.x] = (threadIdx.x & 1) ? 0u : 0x7F800000u;  // min=+inf, max=0
    }
    int gid = blockIdx.x * blockDim.x + threadIdx.x;
    if (gid >= Bn * Nn * 4) return;
    int c4 = gid & 3;
    int bn = gid >> 2;            // b*N + n
    int b  = bn / Nn;
    int n  = bn - b * Nn;

    const float4* x4 = (const float4*)x;
    float4 s  = make_float4(0.f, 0.f, 0.f, 0.f);
    float4 ss = make_float4(0.f, 0.f, 0.f, 0.f);
    int base = (b * Tn) * Nn;     // row units of 16 floats
#pragma unroll
    for (int t = 0; t < Tn; ++t) {
        float4 v = x4[(base + t * Nn + n) * 4 + c4];
        s.x += v.x; s.y += v.y; s.z += v.z; s.w += v.w;
        ss.x += v.x * v.x; ss.y += v.y * v.y; ss.z += v.z * v.z; ss.w += v.w * v.w;
    }
    const float inv = 1.0f / (float)Tn;
    float4 m, sd;
    m.x = s.x * inv; m.y = s.y * inv; m.z = s.z * inv; m.w = s.w * inv;
    sd.x = sqrtf(fmaxf(ss.x * inv - m.x * m.x, 0.f));
    sd.y = sqrtf(fmaxf(ss.y * inv - m.y * m.y, 0.f));
    sd.z = sqrtf(fmaxf(ss.z * inv - m.z * m.z, 0.f));
    sd.w = sqrtf(fmaxf(ss.w * inv - m.w * m.w, 0.f));

    float p = m.x * m.x + m.y * m.y + m.z * m.z + m.w * m.w
            + sd.x * sd.x + sd.y * sd.y + sd.z * sd.z + sd.w * sd.w;
    p += __shfl_xor(p, 1);
    p += __shfl_xor(p, 2);
    float rn = 1.0f / fmaxf(sqrtf(p), COS_EPS);

    H8 o;
    o.h2[0] = __floats2half2_rn(m.x * rn,  m.y * rn);
    o.h2[1] = __floats2half2_rn(m.z * rn,  m.w * rn);
    o.h2[2] = __floats2half2_rn(sd.x * rn, sd.y * rn);
    o.h2[3] = __floats2half2_rn(sd.z * rn, sd.w * rn);
    feat[(n * 4 + b) * 4 + c4] = o.f4;    // 16 B chunk c4 of row (n,b)
}

// Kernel 2: one WAVE per edge, all 4 batches. Lane l: g=l>>2 member slot,
// q=l&3 chunk. A member gather = 256 contiguous bytes (2 cache lines)
// covering all 4 batches.
__global__ void edge_sim_kernel(const float4* __restrict__ feat,
                                const int* __restrict__ members,
                                const int* __restrict__ centers,
                                const int* __restrict__ offsets,
                                float* __restrict__ ms) {
    int tid  = blockIdx.x * blockDim.x + threadIdx.x;
    int e    = tid >> 6;
    if (e >= En) return;
    int lane = threadIdx.x & 63;
    int g    = lane >> 2;
    int q    = lane & 3;

    int off0 = offsets[e];
    int off1 = offsets[e + 1];
    int deg  = off1 - off0;
    int cn   = centers[e];

    // center chunks (this lane's q-chunk) for all batches, as floats
    float cf[Bn][8];
#pragma unroll
    for (int b_ = 0; b_ < Bn; ++b_) {
        H8 u; u.f4 = feat[(cn * 4 + b_) * 4 + q];
#pragma unroll
        for (int i = 0; i < 4; ++i) {
            float2 p = __half22float2(u.h2[i]);
            cf[b_][2 * i]     = p.x;
            cf[b_][2 * i + 1] = p.y;
        }
    }

    float sums[Bn] = {0.f, 0.f, 0.f, 0.f};
    for (int m0 = g; m0 < deg; m0 += 16) {
        int mn = members[off0 + m0];
#pragma unroll
        for (int b_ = 0; b_ < Bn; ++b_) {
            H8 u; u.f4 = feat[(mn * 4 + b_) * 4 + q];
            float d = 0.f;
#pragma unroll
            for (int i = 0; i < 4; ++i) {
                float2 p = __half22float2(u.h2[i]);
                d += p.x * cf[b_][2 * i] + p.y * cf[b_][2 * i + 1];
            }
            d += __shfl_xor(d, 1);
            d += __shfl_xor(d, 2);   // all 4 lanes of group g hold full 32-dot
            sums[b_] += fminf(fmaxf(d, 0.f), 1.f);
        }
    }
    // reduce across the 16 groups (strides 4..32); q-copies don't double-count
#pragma unroll
    for (int b_ = 0; b_ < Bn; ++b_) {
        float s = sums[b_];
        s += __shfl_xor(s, 4);
        s += __shfl_xor(s, 8);
        s += __shfl_xor(s, 16);
        s += __shfl_xor(s, 32);
        sums[b_] = s;
    }
    if (lane == 0) {
        float invd = 1.0f / fmaxf((float)deg, 1.0f);
#pragma unroll
        for (int b_ = 0; b_ < Bn; ++b_) ms[b_ * En + e] = sums[b_] * invd;
    }
}

// Kernel 3: per-batch min/max via uint-bit atomics (values >= 0 so uint order
// == float order). 64 blocks per batch, 2 atomics per block.
__global__ void minmax_kernel(const float* __restrict__ ms, unsigned* __restrict__ mm) {
    int b = blockIdx.x >> 6;
    int j = blockIdx.x & 63;
    const float* p = ms + b * En;
    float lo = INFINITY, hi = 0.f;
    for (int i = j * blockDim.x + threadIdx.x; i < En; i += 64 * 256) {
        float v = p[i];
        lo = fminf(lo, v);
        hi = fmaxf(hi, v);
    }
#pragma unroll
    for (int m = 1; m < 64; m <<= 1) {
        lo = fminf(lo, __shfl_xor(lo, m));
        hi = fmaxf(hi, __shfl_xor(hi, m));
    }
    __shared__ float slo[4], shi[4];
    int wid  = threadIdx.x >> 6;
    int lane = threadIdx.x & 63;
    if (lane == 0) { slo[wid] = lo; shi[wid] = hi; }
    __syncthreads();
    if (threadIdx.x == 0) {
        float flo = fminf(fminf(slo[0], slo[1]), fminf(slo[2], slo[3]));
        float fhi = fmaxf(fmaxf(shi[0], shi[1]), fmaxf(shi[2], shi[3]));
        atomicMin(&mm[b * 2],     __float_as_uint(flo));
        atomicMax(&mm[b * 2 + 1], __float_as_uint(fhi));
    }
}

// Kernel 4: out = W * (1 + LAM * minmax-normed mean_sim)
__global__ void out_kernel(const float* __restrict__ ms, const unsigned* __restrict__ mm,
                           const float* __restrict__ W, float* __restrict__ out) {
    int gid = blockIdx.x * blockDim.x + threadIdx.x;
    if (gid >= Bn * En) return;
    int b = gid / En;
    int e = gid - b * En;
    float smin = __uint_as_float(mm[b * 2]);
    float smax = __uint_as_float(mm[b * 2 + 1]);
    float v = (ms[gid] - smin) / (smax - smin + NORM_EPS);
    out[gid] = W[e] * (1.0f + LAM * v);
}

extern "C" void kernel_launch(void* const* d_in, const int* in_sizes, int n_in,
                              void* d_out, int out_size, void* d_ws, size_t ws_size,
                              hipStream_t stream) {
    const float* x_raw        = (const float*)d_in[0];
    // d_in[1] = H, unused
    const float* W            = (const float*)d_in[2];
    const int*   edge_members = (const int*)d_in[3];
    const int*   edge_centers = (const int*)d_in[4];
    const int*   edge_offsets = (const int*)d_in[5];
    float*       out          = (float*)d_out;

    float4*   feat = (float4*)d_ws;                       // N*B*64 B = 12.8 MB
    float*    ms   = (float*)((char*)d_ws + (size_t)Nn * Bn * 64);  // B*E floats
    unsigned* mm   = (unsigned*)(ms + (size_t)Bn * En);   // 2*B uints

    {
        int total = Bn * Nn * 4;
        feat_kernel<<<(total + 255) / 256, 256, 0, stream>>>(x_raw, feat, mm);
    }
    {
        long long threads = (long long)En * 64;           // one wave per edge
        int blocks = (int)((threads + 255) / 256);
        edge_sim_kernel<<<blocks, 256, 0, stream>>>(
            feat, edge_members, edge_centers, edge_offsets, ms);
    }
    minmax_kernel<<<Bn * 64, 256, 0, stream>>>(ms, mm);
    {
        int total = Bn * En;
        out_kernel<<<(total + 255) / 256, 256, 0, stream>>>(ms, mm, W, out);
    }
}